// Round 7
// baseline (431.961 us; speedup 1.0000x reference)
//
#include <hip/hip_runtime.h>

// MUTAN fused bilinear (low-rank Tucker) + ReLU + LayerNorm, MI355X gfx950.
// Round 7: rank-split grid (z=2 -> 2 independent blocks/CU, 4 waves/SIMD)
// for cross-block latency hiding; ReLU deferred to LN (sums partials);
// s_setprio(1) around MFMA cluster (T5). Frag-major pre-pack as before.

typedef unsigned short u16;
typedef __attribute__((ext_vector_type(8))) short bf16x8;   // 8 bf16 = 4 VGPRs
typedef __attribute__((ext_vector_type(4))) float f32x4;    // MFMA C/D

constexpr int Bq = 4096;   // batch
constexpr int D  = 1024;   // contraction dim
constexpr int Zq = 1024;   // output dim
constexpr int Rk = 16;     // rank
// A tile (per kt): 1024 chunks of 16B, chunk = ((wm*4+mf)*2+kk)*64 + lane
//   row = wm*64+mf*16+(l&15), k = kk*32+(l>>4)*8
// B tile (per kt): 1024 chunks, chunk = ((wn*2+nf)*2+kk)*64 + lane
//   col = wn*32+nf*16+(l&15), k = kk*32+(l>>4)*8

typedef const __attribute__((address_space(1))) void* gas_t;
typedef __attribute__((address_space(3))) void* las_t;

__device__ __forceinline__ u16 f2b(float f) {
  union { float f; unsigned u; } c; c.f = f;
  unsigned r = (c.u + 0x7FFFu + ((c.u >> 16) & 1u)) >> 16;  // RNE
  return (u16)r;
}

// ---- prep: hd/hp [4096][1024] f32 -> fragment-major bf16 ----
// layout: [bx(32)][kt(16)][chunk(1024)][8]; 524288 chunks per tensor.
__global__ __launch_bounds__(256) void fm_pack_A(const float* __restrict__ src,
                                                 u16* __restrict__ dst) {
  const int g  = blockIdx.x * 256 + threadIdx.x;      // chunk id
  const int c  = g & 1023;
  const int kt = (g >> 10) & 15;
  const int bx = g >> 14;
  const int l  = c & 63;
  const int kk = (c >> 6) & 1;
  const int mf = (c >> 7) & 3;
  const int wm = (c >> 9) & 1;
  const int row = wm * 64 + mf * 16 + (l & 15);
  const int kel = kk * 32 + ((l >> 4) << 3);
  const float* s = src + (size_t)(bx * 128 + row) * D + kt * 64 + kel;
  const float4 f0 = *(const float4*)s;
  const float4 f1 = *(const float4*)(s + 4);
  union { u16 h[8]; uint4 u; } o;
  o.h[0] = f2b(f0.x); o.h[1] = f2b(f0.y); o.h[2] = f2b(f0.z); o.h[3] = f2b(f0.w);
  o.h[4] = f2b(f1.x); o.h[5] = f2b(f1.y); o.h[6] = f2b(f1.z); o.h[7] = f2b(f1.w);
  *(uint4*)(dst + (size_t)g * 8) = o.u;
}

// ---- prep: U/V [r][k][z] f32 -> fragment-major bf16 ----
// layout: [r(16)][jt(8)][kt(16)][chunk(1024)][8]; 2097152 chunks per tensor.
__global__ __launch_bounds__(256) void fm_pack_B(const float* __restrict__ src,
                                                 u16* __restrict__ dst) {
  const int g  = blockIdx.x * 256 + threadIdx.x;      // chunk id
  const int c  = g & 1023;
  const int kt = (g >> 10) & 15;
  const int jt = (g >> 14) & 7;
  const int r  = g >> 17;
  const int l  = c & 63;
  const int kk = (c >> 6) & 1;
  const int nf = (c >> 7) & 1;
  const int wn = (c >> 8) & 3;
  const int j  = jt * 128 + wn * 32 + nf * 16 + (l & 15);
  const int kg = kt * 64 + kk * 32 + ((l >> 4) << 3);
  const float* s = src + (size_t)r * (D * Zq) + (size_t)kg * Zq + j;
  union { u16 h[8]; uint4 u; } o;
  #pragma unroll
  for (int e = 0; e < 8; ++e) o.h[e] = f2b(s[(size_t)e * Zq]);
  *(uint4*)(dst + (size_t)g * 8) = o.u;
}

#define STAGE(buf, ktile) do {                                                   \
    const int _o = (ktile) * 8192;                                               \
    __builtin_amdgcn_global_load_lds((gas_t)(hdp + _o + c0 * 8), (las_t)&sT[buf][0][c0 * 8], 16, 0, 0); \
    __builtin_amdgcn_global_load_lds((gas_t)(hdp + _o + c1 * 8), (las_t)&sT[buf][0][c1 * 8], 16, 0, 0); \
    __builtin_amdgcn_global_load_lds((gas_t)(hpp + _o + c0 * 8), (las_t)&sT[buf][1][c0 * 8], 16, 0, 0); \
    __builtin_amdgcn_global_load_lds((gas_t)(hpp + _o + c1 * 8), (las_t)&sT[buf][1][c1 * 8], 16, 0, 0); \
  } while (0)

// stp counts K-steps within this block's rank range; rank = rbase + stp/16
#define LOADB(BU, BV, stp) do {                                                  \
    const u16* _up = Ub + (size_t)(rbase + ((stp) >> 4)) * rstride + ((stp) & 15) * 8192; \
    const u16* _vp = Vb + (size_t)(rbase + ((stp) >> 4)) * rstride + ((stp) & 15) * 8192; \
    _Pragma("unroll")                                                            \
    for (int nf = 0; nf < 2; ++nf)                                               \
      _Pragma("unroll")                                                          \
      for (int kk = 0; kk < 2; ++kk) {                                           \
        BU[nf][kk] = *(const bf16x8*)(_up + bco[nf][kk]);                        \
        BV[nf][kk] = *(const bf16x8*)(_vp + bco[nf][kk]);                        \
      }                                                                          \
  } while (0)

#define COMPUTE(buf, BU, BV) do {                                                \
    const u16* tA = sT[buf][0];                                                  \
    const u16* tB = sT[buf][1];                                                  \
    _Pragma("unroll")                                                            \
    for (int kk = 0; kk < 2; ++kk) {                                             \
      bf16x8 a[4], b[4];                                                         \
      _Pragma("unroll")                                                          \
      for (int mf = 0; mf < 4; ++mf) {                                           \
        const int ao = (((wm * 4 + mf) * 2 + kk) * 64 + lane) * 8;               \
        a[mf] = *(const bf16x8*)(tA + ao);                                       \
        b[mf] = *(const bf16x8*)(tB + ao);                                       \
      }                                                                          \
      __builtin_amdgcn_s_setprio(1);                                             \
      _Pragma("unroll")                                                          \
      for (int mf = 0; mf < 4; ++mf)                                             \
        _Pragma("unroll")                                                        \
        for (int nf = 0; nf < 2; ++nf) {                                         \
          au[mf][nf] = __builtin_amdgcn_mfma_f32_16x16x32_bf16(a[mf], BU[nf][kk], au[mf][nf], 0, 0, 0); \
          av[mf][nf] = __builtin_amdgcn_mfma_f32_16x16x32_bf16(b[mf], BV[nf][kk], av[mf][nf], 0, 0, 0); \
        }                                                                        \
      __builtin_amdgcn_s_setprio(0);                                             \
    }                                                                            \
  } while (0)

// ---- main: fused bilinear, bf16 MFMA 16x16x32 ----
// grid (32 bx, 8 jt, NZ). NZ=2: each z-block does 8 ranks -> 512 blocks =
// 2 independent blocks/CU (4 waves/SIMD). Raw partial sums stored (ReLU in LN).
// 512 thr = 8 waves (2m x 4n), wave tile 64x32. A: LDS dbuf staged 1 ahead.
// B: VGPR, pipelined 1 step ahead (ping-pong reg sets, 2-step unroll).
__global__ __launch_bounds__(512, 2) void fused_bilinear(
    const u16* __restrict__ hdf, const u16* __restrict__ hpf,
    const u16* __restrict__ Uf, const u16* __restrict__ Vf,
    float* __restrict__ out0, float* __restrict__ out1, int rpb)
{
  __shared__ __align__(16) u16 sT[2][2][128 * 64];   // 64 KB

  const int tid  = threadIdx.x;
  const int lane = tid & 63;
  const int wv   = tid >> 6;
  const int wm   = wv >> 2;               // 0..1
  const int wn   = wv & 3;                // 0..3

  const int bx = blockIdx.x;              // 0..31 (XCD = bx%8)
  const int jt = blockIdx.y;              // 0..7
  const int rz = blockIdx.z;              // rank-half
  float* outp = rz ? out1 : out0;
  const int rbase = rz * rpb;
  const int steps = rpb * 16;             // K-steps in this block

  const u16* hdp = hdf + (size_t)bx * 16 * 8192;     // [kt][1024 chunks][8]
  const u16* hpp = hpf + (size_t)bx * 16 * 8192;
  const u16* Ub  = Uf + (size_t)jt * 16 * 8192;      // + r*rstride + kt*8192
  const u16* Vb  = Vf + (size_t)jt * 16 * 8192;
  const size_t rstride = (size_t)8 * 16 * 8192;

  const int c0 = wv * 128 + lane;
  const int c1 = c0 + 64;

  int bco[2][2];
  #pragma unroll
  for (int nf = 0; nf < 2; ++nf)
    #pragma unroll
    for (int kk = 0; kk < 2; ++kk)
      bco[nf][kk] = (((wn * 2 + nf) * 2 + kk) * 64 + lane) * 8;

  f32x4 acc[4][2], au[4][2], av[4][2];
  #pragma unroll
  for (int mf = 0; mf < 4; ++mf)
    #pragma unroll
    for (int nf = 0; nf < 2; ++nf) {
      acc[mf][nf] = (f32x4){0.f, 0.f, 0.f, 0.f};
      au[mf][nf]  = (f32x4){0.f, 0.f, 0.f, 0.f};
      av[mf][nf]  = (f32x4){0.f, 0.f, 0.f, 0.f};
    }

  bf16x8 bu0[2][2], bv0[2][2], bu1[2][2], bv1[2][2];

  // prologue: stage step 0 tile, load B(step 0)
  STAGE(0, 0);
  LOADB(bu0, bv0, 0);
  __syncthreads();

  #pragma unroll 1
  for (int it = 0; it < steps / 2; ++it) {
    const int s0 = it * 2;        // even step -> buf 0, reg set 0
    const int s1 = s0 + 1;        // odd step  -> buf 1, reg set 1

    // phase A: prefetch s1, compute s0
    STAGE(1, s1 & 15);
    LOADB(bu1, bv1, s1);
    COMPUTE(0, bu0, bv0);
    __syncthreads();

    // phase B: prefetch s1+1, compute s1
    if (s1 < steps - 1) {
      STAGE(0, (s1 + 1) & 15);
      LOADB(bu0, bv0, s1 + 1);
    }
    COMPUTE(1, bu1, bv1);
    // rank boundary: s1&15==15 -> au/av hold full K-sum for this rank
    if ((s1 & 15) == 15) {
      #pragma unroll
      for (int mf = 0; mf < 4; ++mf)
        #pragma unroll
        for (int nf = 0; nf < 2; ++nf) {
          #pragma unroll
          for (int i = 0; i < 4; ++i)
            acc[mf][nf][i] += au[mf][nf][i] * av[mf][nf][i];
          au[mf][nf] = (f32x4){0.f, 0.f, 0.f, 0.f};
          av[mf][nf] = (f32x4){0.f, 0.f, 0.f, 0.f};
        }
    }
    __syncthreads();
  }

  // epilogue: store RAW partial (ReLU deferred to LN).
  // C/D: col = lane&15, row = 4*(lane>>4)+i.
  const int brow = bx * 128;
  const int jcol = jt * 128;
  #pragma unroll
  for (int mf = 0; mf < 4; ++mf)
    #pragma unroll
    for (int nf = 0; nf < 2; ++nf) {
      const int gr = brow + wm * 64 + mf * 16 + ((lane >> 4) << 2);
      const int gc = jcol + wn * 32 + nf * 16 + (lane & 15);
      #pragma unroll
      for (int i = 0; i < 4; ++i)
        outp[(size_t)(gr + i) * Zq + gc] = acc[mf][nf][i];
    }
}

// ---- LayerNorm: z = relu(p0 [+ p1]); LN(z) -> out. jnp.var ddof=0. ----
__global__ __launch_bounds__(256) void ln_rows_sum(float* __restrict__ out,
    const float* __restrict__ p1, int split,
    const float* __restrict__ gamma, const float* __restrict__ beta)
{
  const int row = blockIdx.x;
  const int t = threadIdx.x;
  float* o = out + (size_t)row * Zq;
  float4 v = ((const float4*)o)[t];
  if (split) {
    const float4 w = ((const float4*)(p1 + (size_t)row * Zq))[t];
    v.x += w.x; v.y += w.y; v.z += w.z; v.w += w.w;
  }
  v.x = fmaxf(v.x, 0.f); v.y = fmaxf(v.y, 0.f);
  v.z = fmaxf(v.z, 0.f); v.w = fmaxf(v.w, 0.f);
  float s = v.x + v.y + v.z + v.w;
  float q = v.x * v.x + v.y * v.y + v.z * v.z + v.w * v.w;
  #pragma unroll
  for (int off = 32; off > 0; off >>= 1) {
    s += __shfl_xor(s, off);
    q += __shfl_xor(q, off);
  }
  __shared__ float ss[4], sq[4];
  if ((t & 63) == 0) { ss[t >> 6] = s; sq[t >> 6] = q; }
  __syncthreads();
  s = ss[0] + ss[1] + ss[2] + ss[3];
  q = sq[0] + sq[1] + sq[2] + sq[3];
  const float mean = s * (1.f / Zq);
  float var = q * (1.f / Zq) - mean * mean;
  var = fmaxf(var, 0.f);
  const float rstd = rsqrtf(var + 1e-5f);
  const float4 g  = ((const float4*)gamma)[t];
  const float4 bb = ((const float4*)beta)[t];
  v.x = (v.x - mean) * rstd * g.x + bb.x;
  v.y = (v.y - mean) * rstd * g.y + bb.y;
  v.z = (v.z - mean) * rstd * g.z + bb.z;
  v.w = (v.w - mean) * rstd * g.w + bb.w;
  ((float4*)o)[t] = v;
}

// ---- fallback (tiny ws): plain f32, correct but slow ----
__global__ __launch_bounds__(256) void fallback_bilinear(
    const float* __restrict__ hd, const float* __restrict__ hp,
    const float* __restrict__ U, const float* __restrict__ V,
    float* __restrict__ out)
{
  const int j  = blockIdx.x * 256 + threadIdx.x;
  const int b0 = blockIdx.y * 8;
  float acc[8] = {0.f, 0.f, 0.f, 0.f, 0.f, 0.f, 0.f, 0.f};
  for (int r = 0; r < Rk; ++r) {
    float u[8] = {0.f}, v[8] = {0.f};
    const float* Up = U + (size_t)r * (D * Zq) + j;
    const float* Vp = V + (size_t)r * (D * Zq) + j;
    for (int k = 0; k < D; ++k) {
      const float uu = Up[(size_t)k * Zq];
      const float vv = Vp[(size_t)k * Zq];
      #pragma unroll
      for (int bi = 0; bi < 8; ++bi) {
        u[bi] = fmaf(hd[(size_t)(b0 + bi) * D + k], uu, u[bi]);
        v[bi] = fmaf(hp[(size_t)(b0 + bi) * D + k], vv, v[bi]);
      }
    }
    #pragma unroll
    for (int bi = 0; bi < 8; ++bi) acc[bi] += u[bi] * v[bi];
  }
  #pragma unroll
  for (int bi = 0; bi < 8; ++bi)
    out[(size_t)(b0 + bi) * Zq + j] = acc[bi];   // raw; ReLU in LN
}

extern "C" void kernel_launch(void* const* d_in, const int* in_sizes, int n_in,
                              void* d_out, int out_size, void* d_ws, size_t ws_size,
                              hipStream_t stream) {
  const float* hd    = (const float*)d_in[0];   // [4096][1024]
  const float* hp    = (const float*)d_in[1];   // [4096][1024]
  const float* U     = (const float*)d_in[2];   // [16][1024][1024]
  const float* V     = (const float*)d_in[3];   // [16][1024][1024]
  const float* gamma = (const float*)d_in[4];   // [1024]
  const float* beta  = (const float*)d_in[5];   // [1024]
  float* out = (float*)d_out;                   // [4096][1024] f32

  const size_t need_pack  = 80ull << 20;  // hd,hp fm (16MB) + U,V fm (64MB)
  const size_t need_split = 96ull << 20;  // + 16MB rank-half partial
  if (ws_size >= need_pack) {
    u16* hdf = (u16*)d_ws;                   // 4M elems
    u16* hpf = hdf + (size_t)Bq * D;
    u16* Ufm = hpf + (size_t)Bq * D;         // 16M elems each
    u16* Vfm = Ufm + (size_t)Rk * D * Zq;
    float* part1 = (float*)((char*)d_ws + need_pack);

    fm_pack_A<<<2048, 256, 0, stream>>>(hd, hdf);
    fm_pack_A<<<2048, 256, 0, stream>>>(hp, hpf);
    fm_pack_B<<<8192, 256, 0, stream>>>(U, Ufm);
    fm_pack_B<<<8192, 256, 0, stream>>>(V, Vfm);
    if (ws_size >= need_split) {
      fused_bilinear<<<dim3(32, 8, 2), 512, 0, stream>>>(hdf, hpf, Ufm, Vfm,
                                                         out, part1, Rk / 2);
      ln_rows_sum<<<Bq, 256, 0, stream>>>(out, part1, 1, gamma, beta);
    } else {
      fused_bilinear<<<dim3(32, 8, 1), 512, 0, stream>>>(hdf, hpf, Ufm, Vfm,
                                                         out, out, Rk);
      ln_rows_sum<<<Bq, 256, 0, stream>>>(out, out, 0, gamma, beta);
    }
  } else {
    fallback_bilinear<<<dim3(Zq / 256, Bq / 8), 256, 0, stream>>>(hd, hp, U, V, out);
    ln_rows_sum<<<Bq, 256, 0, stream>>>(out, out, 0, gamma, beta);
  }
}

// Round 8
// 419.834 us; speedup vs baseline: 1.0289x; 1.0289x over previous
//
#include <hip/hip_runtime.h>

// MUTAN fused bilinear (low-rank Tucker) + ReLU + LayerNorm, MI355X gfx950.
// Round 8: T3/T4 counted-vmcnt schedule. Raw s_barrier (no compiler drain);
// per phase issue 12 VMEM (4 gload_lds + 8 B-loads) for step s+2, then
// s_waitcnt vmcnt(12) so only the s+1 group is retired -- the new 12 stay in
// flight across the barrier. setprio(1) around MFMA cluster (T5, pays on
// phase-split schedules). Shape = round 6 (grid 32x8, 512 thr, B-reg pingpong).

typedef unsigned short u16;
typedef __attribute__((ext_vector_type(8))) short bf16x8;   // 8 bf16 = 4 VGPRs
typedef __attribute__((ext_vector_type(4))) float f32x4;    // MFMA C/D

constexpr int Bq = 4096;   // batch
constexpr int D  = 1024;   // contraction dim
constexpr int Zq = 1024;   // output dim
constexpr int Rk = 16;     // rank
// A tile (per kt): 1024 chunks of 16B, chunk = ((wm*4+mf)*2+kk)*64 + lane
//   row = wm*64+mf*16+(l&15), k = kk*32+(l>>4)*8
// B tile (per kt): 1024 chunks, chunk = ((wn*2+nf)*2+kk)*64 + lane
//   col = wn*32+nf*16+(l&15), k = kk*32+(l>>4)*8

typedef const __attribute__((address_space(1))) void* gas_t;
typedef __attribute__((address_space(3))) void* las_t;

__device__ __forceinline__ u16 f2b(float f) {
  union { float f; unsigned u; } c; c.f = f;
  unsigned r = (c.u + 0x7FFFu + ((c.u >> 16) & 1u)) >> 16;  // RNE
  return (u16)r;
}

// ---- prep: hd/hp [4096][1024] f32 -> fragment-major bf16 ----
// layout: [bx(32)][kt(16)][chunk(1024)][8]; 524288 chunks per tensor.
__global__ __launch_bounds__(256) void fm_pack_A(const float* __restrict__ src,
                                                 u16* __restrict__ dst) {
  const int g  = blockIdx.x * 256 + threadIdx.x;      // chunk id
  const int c  = g & 1023;
  const int kt = (g >> 10) & 15;
  const int bx = g >> 14;
  const int l  = c & 63;
  const int kk = (c >> 6) & 1;
  const int mf = (c >> 7) & 3;
  const int wm = (c >> 9) & 1;
  const int row = wm * 64 + mf * 16 + (l & 15);
  const int kel = kk * 32 + ((l >> 4) << 3);
  const float* s = src + (size_t)(bx * 128 + row) * D + kt * 64 + kel;
  const float4 f0 = *(const float4*)s;
  const float4 f1 = *(const float4*)(s + 4);
  union { u16 h[8]; uint4 u; } o;
  o.h[0] = f2b(f0.x); o.h[1] = f2b(f0.y); o.h[2] = f2b(f0.z); o.h[3] = f2b(f0.w);
  o.h[4] = f2b(f1.x); o.h[5] = f2b(f1.y); o.h[6] = f2b(f1.z); o.h[7] = f2b(f1.w);
  *(uint4*)(dst + (size_t)g * 8) = o.u;
}

// ---- prep: U/V [r][k][z] f32 -> fragment-major bf16 ----
// layout: [r(16)][jt(8)][kt(16)][chunk(1024)][8]; 2097152 chunks per tensor.
__global__ __launch_bounds__(256) void fm_pack_B(const float* __restrict__ src,
                                                 u16* __restrict__ dst) {
  const int g  = blockIdx.x * 256 + threadIdx.x;      // chunk id
  const int c  = g & 1023;
  const int kt = (g >> 10) & 15;
  const int jt = (g >> 14) & 7;
  const int r  = g >> 17;
  const int l  = c & 63;
  const int kk = (c >> 6) & 1;
  const int nf = (c >> 7) & 1;
  const int wn = (c >> 8) & 3;
  const int j  = jt * 128 + wn * 32 + nf * 16 + (l & 15);
  const int kg = kt * 64 + kk * 32 + ((l >> 4) << 3);
  const float* s = src + (size_t)r * (D * Zq) + (size_t)kg * Zq + j;
  union { u16 h[8]; uint4 u; } o;
  #pragma unroll
  for (int e = 0; e < 8; ++e) o.h[e] = f2b(s[(size_t)e * Zq]);
  *(uint4*)(dst + (size_t)g * 8) = o.u;
}

#define STAGE(buf, ktile) do {                                                   \
    const int _o = (ktile) * 8192;                                               \
    __builtin_amdgcn_global_load_lds((gas_t)(hdp + _o + c0 * 8), (las_t)&sT[buf][0][c0 * 8], 16, 0, 0); \
    __builtin_amdgcn_global_load_lds((gas_t)(hdp + _o + c1 * 8), (las_t)&sT[buf][0][c1 * 8], 16, 0, 0); \
    __builtin_amdgcn_global_load_lds((gas_t)(hpp + _o + c0 * 8), (las_t)&sT[buf][1][c0 * 8], 16, 0, 0); \
    __builtin_amdgcn_global_load_lds((gas_t)(hpp + _o + c1 * 8), (las_t)&sT[buf][1][c1 * 8], 16, 0, 0); \
  } while (0)

#define LOADB(BU, BV, stp) do {                                                  \
    const u16* _up = Ub + (size_t)((stp) >> 4) * rstride + ((stp) & 15) * 8192;  \
    const u16* _vp = Vb + (size_t)((stp) >> 4) * rstride + ((stp) & 15) * 8192;  \
    _Pragma("unroll")                                                            \
    for (int nf = 0; nf < 2; ++nf)                                               \
      _Pragma("unroll")                                                          \
      for (int kk = 0; kk < 2; ++kk) {                                           \
        BU[nf][kk] = *(const bf16x8*)(_up + bco[nf][kk]);                        \
        BV[nf][kk] = *(const bf16x8*)(_vp + bco[nf][kk]);                        \
      }                                                                          \
  } while (0)

#define COMPUTE(buf, BU, BV) do {                                                \
    const u16* tA = sT[buf][0];                                                  \
    const u16* tB = sT[buf][1];                                                  \
    _Pragma("unroll")                                                            \
    for (int kk = 0; kk < 2; ++kk) {                                             \
      bf16x8 a[4], b[4];                                                         \
      _Pragma("unroll")                                                          \
      for (int mf = 0; mf < 4; ++mf) {                                           \
        const int ao = (((wm * 4 + mf) * 2 + kk) * 64 + lane) * 8;               \
        a[mf] = *(const bf16x8*)(tA + ao);                                       \
        b[mf] = *(const bf16x8*)(tB + ao);                                       \
      }                                                                          \
      __builtin_amdgcn_s_setprio(1);                                             \
      _Pragma("unroll")                                                          \
      for (int mf = 0; mf < 4; ++mf)                                             \
        _Pragma("unroll")                                                        \
        for (int nf = 0; nf < 2; ++nf) {                                         \
          au[mf][nf] = __builtin_amdgcn_mfma_f32_16x16x32_bf16(a[mf], BU[nf][kk], au[mf][nf], 0, 0, 0); \
          av[mf][nf] = __builtin_amdgcn_mfma_f32_16x16x32_bf16(b[mf], BV[nf][kk], av[mf][nf], 0, 0, 0); \
        }                                                                        \
      __builtin_amdgcn_s_setprio(0);                                             \
    }                                                                            \
  } while (0)

#define SFENCE() __builtin_amdgcn_sched_barrier(0)
#define BAR()    __builtin_amdgcn_s_barrier()

// one phase: compute step s from (buf,Bregs); issue s+2 into same slots;
// wait the s+1 group (12 outstanding kept in flight) and publish.
#define PHASE(buf, BU, BV, s) do {                                               \
    COMPUTE(buf, BU, BV);                                                        \
    BAR(); SFENCE();                                                             \
    if ((s) + 2 < 256) {                                                         \
      STAGE(buf, ((s) + 2) & 15);                                                \
      LOADB(BU, BV, (s) + 2);                                                    \
      SFENCE();                                                                  \
      asm volatile("s_waitcnt vmcnt(12)" ::: "memory");                          \
    } else {                                                                     \
      asm volatile("s_waitcnt vmcnt(0)" ::: "memory");                           \
    }                                                                            \
    SFENCE();                                                                    \
    BAR(); SFENCE();                                                             \
  } while (0)

// ---- main: fused bilinear, bf16 MFMA 16x16x32 ----
// grid (32 bx, 8 jt) = 256 blocks = 1/CU. 512 thr = 8 waves (2m x 4n),
// wave tile 64x32 = 4mf x 2nf. A: LDS dbuf. B: VGPR pingpong. Counted-vmcnt
// schedule: 2-phase prefetch distance, never drain to 0 in main loop.
__global__ __launch_bounds__(512, 2) void fused_bilinear(
    const u16* __restrict__ hdf, const u16* __restrict__ hpf,
    const u16* __restrict__ Uf, const u16* __restrict__ Vf,
    float* __restrict__ out)
{
  __shared__ __align__(16) u16 sT[2][2][128 * 64];   // 64 KB

  const int tid  = threadIdx.x;
  const int lane = tid & 63;
  const int wv   = tid >> 6;
  const int wm   = wv >> 2;               // 0..1
  const int wn   = wv & 3;                // 0..3

  const int bx = blockIdx.x;              // 0..31 (XCD = bx%8)
  const int jt = blockIdx.y;              // 0..7

  const u16* hdp = hdf + (size_t)bx * 16 * 8192;     // [kt][1024 chunks][8]
  const u16* hpp = hpf + (size_t)bx * 16 * 8192;
  const u16* Ub  = Uf + (size_t)jt * 16 * 8192;      // + r*rstride + kt*8192
  const u16* Vb  = Vf + (size_t)jt * 16 * 8192;
  const size_t rstride = (size_t)8 * 16 * 8192;

  const int c0 = wv * 128 + lane;
  const int c1 = c0 + 64;

  int bco[2][2];
  #pragma unroll
  for (int nf = 0; nf < 2; ++nf)
    #pragma unroll
    for (int kk = 0; kk < 2; ++kk)
      bco[nf][kk] = (((wn * 2 + nf) * 2 + kk) * 64 + lane) * 8;

  f32x4 acc[4][2], au[4][2], av[4][2];
  #pragma unroll
  for (int mf = 0; mf < 4; ++mf)
    #pragma unroll
    for (int nf = 0; nf < 2; ++nf) {
      acc[mf][nf] = (f32x4){0.f, 0.f, 0.f, 0.f};
      au[mf][nf]  = (f32x4){0.f, 0.f, 0.f, 0.f};
      av[mf][nf]  = (f32x4){0.f, 0.f, 0.f, 0.f};
    }

  bf16x8 bu0[2][2], bv0[2][2], bu1[2][2], bv1[2][2];

  // prologue: fill 2-deep pipeline (24 VMEM in flight), wait oldest 12.
  STAGE(0, 0); LOADB(bu0, bv0, 0);
  STAGE(1, 1); LOADB(bu1, bv1, 1);
  SFENCE();
  asm volatile("s_waitcnt vmcnt(12)" ::: "memory");
  SFENCE();
  BAR(); SFENCE();

  #pragma unroll 1
  for (int it = 0; it < 128; ++it) {
    const int s0 = it * 2;        // even step -> buf 0, reg set 0
    const int s1 = s0 + 1;        // odd step  -> buf 1, reg set 1

    PHASE(0, bu0, bv0, s0);
    PHASE(1, bu1, bv1, s1);

    // rank boundary (steps/rank = 16, so boundary is always an odd step)
    if ((s1 & 15) == 15) {
      #pragma unroll
      for (int mf = 0; mf < 4; ++mf)
        #pragma unroll
        for (int nf = 0; nf < 2; ++nf) {
          #pragma unroll
          for (int i = 0; i < 4; ++i)
            acc[mf][nf][i] += au[mf][nf][i] * av[mf][nf][i];
          au[mf][nf] = (f32x4){0.f, 0.f, 0.f, 0.f};
          av[mf][nf] = (f32x4){0.f, 0.f, 0.f, 0.f};
        }
    }
  }

  // epilogue: store RAW sum (ReLU in LN). C/D: col = lane&15, row = 4*(lane>>4)+i.
  const int brow = bx * 128;
  const int jcol = jt * 128;
  #pragma unroll
  for (int mf = 0; mf < 4; ++mf)
    #pragma unroll
    for (int nf = 0; nf < 2; ++nf) {
      const int gr = brow + wm * 64 + mf * 16 + ((lane >> 4) << 2);
      const int gc = jcol + wn * 32 + nf * 16 + (lane & 15);
      #pragma unroll
      for (int i = 0; i < 4; ++i)
        out[(size_t)(gr + i) * Zq + gc] = acc[mf][nf][i];
    }
}

// ---- LayerNorm: z = relu(p); LN(z) -> out, in place. jnp.var ddof=0. ----
__global__ __launch_bounds__(256) void ln_rows(float* __restrict__ out,
    const float* __restrict__ gamma, const float* __restrict__ beta)
{
  const int row = blockIdx.x;
  const int t = threadIdx.x;
  float* o = out + (size_t)row * Zq;
  float4 v = ((const float4*)o)[t];
  v.x = fmaxf(v.x, 0.f); v.y = fmaxf(v.y, 0.f);
  v.z = fmaxf(v.z, 0.f); v.w = fmaxf(v.w, 0.f);
  float s = v.x + v.y + v.z + v.w;
  float q = v.x * v.x + v.y * v.y + v.z * v.z + v.w * v.w;
  #pragma unroll
  for (int off = 32; off > 0; off >>= 1) {
    s += __shfl_xor(s, off);
    q += __shfl_xor(q, off);
  }
  __shared__ float ss[4], sq[4];
  if ((t & 63) == 0) { ss[t >> 6] = s; sq[t >> 6] = q; }
  __syncthreads();
  s = ss[0] + ss[1] + ss[2] + ss[3];
  q = sq[0] + sq[1] + sq[2] + sq[3];
  const float mean = s * (1.f / Zq);
  float var = q * (1.f / Zq) - mean * mean;
  var = fmaxf(var, 0.f);
  const float rstd = rsqrtf(var + 1e-5f);
  const float4 g  = ((const float4*)gamma)[t];
  const float4 bb = ((const float4*)beta)[t];
  v.x = (v.x - mean) * rstd * g.x + bb.x;
  v.y = (v.y - mean) * rstd * g.y + bb.y;
  v.z = (v.z - mean) * rstd * g.z + bb.z;
  v.w = (v.w - mean) * rstd * g.w + bb.w;
  ((float4*)o)[t] = v;
}

// ---- fallback (tiny ws): plain f32, correct but slow ----
__global__ __launch_bounds__(256) void fallback_bilinear(
    const float* __restrict__ hd, const float* __restrict__ hp,
    const float* __restrict__ U, const float* __restrict__ V,
    float* __restrict__ out)
{
  const int j  = blockIdx.x * 256 + threadIdx.x;
  const int b0 = blockIdx.y * 8;
  float acc[8] = {0.f, 0.f, 0.f, 0.f, 0.f, 0.f, 0.f, 0.f};
  for (int r = 0; r < Rk; ++r) {
    float u[8] = {0.f}, v[8] = {0.f};
    const float* Up = U + (size_t)r * (D * Zq) + j;
    const float* Vp = V + (size_t)r * (D * Zq) + j;
    for (int k = 0; k < D; ++k) {
      const float uu = Up[(size_t)k * Zq];
      const float vv = Vp[(size_t)k * Zq];
      #pragma unroll
      for (int bi = 0; bi < 8; ++bi) {
        u[bi] = fmaf(hd[(size_t)(b0 + bi) * D + k], uu, u[bi]);
        v[bi] = fmaf(hp[(size_t)(b0 + bi) * D + k], vv, v[bi]);
      }
    }
    #pragma unroll
    for (int bi = 0; bi < 8; ++bi) acc[bi] += u[bi] * v[bi];
  }
  #pragma unroll
  for (int bi = 0; bi < 8; ++bi)
    out[(size_t)(b0 + bi) * Zq + j] = acc[bi];   // raw; ReLU in LN
}

extern "C" void kernel_launch(void* const* d_in, const int* in_sizes, int n_in,
                              void* d_out, int out_size, void* d_ws, size_t ws_size,
                              hipStream_t stream) {
  const float* hd    = (const float*)d_in[0];   // [4096][1024]
  const float* hp    = (const float*)d_in[1];   // [4096][1024]
  const float* U     = (const float*)d_in[2];   // [16][1024][1024]
  const float* V     = (const float*)d_in[3];   // [16][1024][1024]
  const float* gamma = (const float*)d_in[4];   // [1024]
  const float* beta  = (const float*)d_in[5];   // [1024]
  float* out = (float*)d_out;                   // [4096][1024] f32

  const size_t need = 80ull << 20;  // hd,hp fm (16MB) + U,V fm (64MB)
  if (ws_size >= need) {
    u16* hdf = (u16*)d_ws;                   // 4M elems
    u16* hpf = hdf + (size_t)Bq * D;
    u16* Ufm = hpf + (size_t)Bq * D;         // 16M elems each
    u16* Vfm = Ufm + (size_t)Rk * D * Zq;

    fm_pack_A<<<2048, 256, 0, stream>>>(hd, hdf);
    fm_pack_A<<<2048, 256, 0, stream>>>(hp, hpf);
    fm_pack_B<<<8192, 256, 0, stream>>>(U, Ufm);
    fm_pack_B<<<8192, 256, 0, stream>>>(V, Vfm);
    fused_bilinear<<<dim3(32, 8), 512, 0, stream>>>(hdf, hpf, Ufm, Vfm, out);
  } else {
    fallback_bilinear<<<dim3(Zq / 256, Bq / 8), 256, 0, stream>>>(hd, hp, U, V, out);
  }
  ln_rows<<<Bq, 256, 0, stream>>>(out, gamma, beta);
}

// Round 9
// 414.893 us; speedup vs baseline: 1.0411x; 1.0119x over previous
//
#include <hip/hip_runtime.h>

// MUTAN fused bilinear (low-rank Tucker) + ReLU + LayerNorm, MI355X gfx950.
// Round 9: m201-style fine-phase schedule. Each K-step = 4 phases of
// {4 ds_read | 2-4 VMEM issue | s_barrier | lgkmcnt(0) | setprio | 8 MFMA |
// s_barrier}. B loads distance-1 with in-step reg recycling (kk0 reloaded at
// ph2, kk1 at ph3 post-MFMA); A-stage distance-2 issued ph3 post-barrier;
// one counted s_waitcnt vmcnt(12) per step (never drain in main loop).

typedef unsigned short u16;
typedef __attribute__((ext_vector_type(8))) short bf16x8;   // 8 bf16 = 4 VGPRs
typedef __attribute__((ext_vector_type(4))) float f32x4;    // MFMA C/D

constexpr int Bq = 4096;   // batch
constexpr int D  = 1024;   // contraction dim
constexpr int Zq = 1024;   // output dim
constexpr int Rk = 16;     // rank
// A tile (per kt): 1024 chunks of 16B, chunk = ((wm*4+mf)*2+kk)*64 + lane
//   row = wm*64+mf*16+(l&15), k = kk*32+(l>>4)*8
// B tile (per kt): 1024 chunks, chunk = ((wn*2+nf)*2+kk)*64 + lane
//   col = wn*32+nf*16+(l&15), k = kk*32+(l>>4)*8

typedef const __attribute__((address_space(1))) void* gas_t;
typedef __attribute__((address_space(3))) void* las_t;

__device__ __forceinline__ u16 f2b(float f) {
  union { float f; unsigned u; } c; c.f = f;
  unsigned r = (c.u + 0x7FFFu + ((c.u >> 16) & 1u)) >> 16;  // RNE
  return (u16)r;
}

// ---- prep: hd/hp [4096][1024] f32 -> fragment-major bf16 ----
__global__ __launch_bounds__(256) void fm_pack_A(const float* __restrict__ src,
                                                 u16* __restrict__ dst) {
  const int g  = blockIdx.x * 256 + threadIdx.x;      // chunk id
  const int c  = g & 1023;
  const int kt = (g >> 10) & 15;
  const int bx = g >> 14;
  const int l  = c & 63;
  const int kk = (c >> 6) & 1;
  const int mf = (c >> 7) & 3;
  const int wm = (c >> 9) & 1;
  const int row = wm * 64 + mf * 16 + (l & 15);
  const int kel = kk * 32 + ((l >> 4) << 3);
  const float* s = src + (size_t)(bx * 128 + row) * D + kt * 64 + kel;
  const float4 f0 = *(const float4*)s;
  const float4 f1 = *(const float4*)(s + 4);
  union { u16 h[8]; uint4 u; } o;
  o.h[0] = f2b(f0.x); o.h[1] = f2b(f0.y); o.h[2] = f2b(f0.z); o.h[3] = f2b(f0.w);
  o.h[4] = f2b(f1.x); o.h[5] = f2b(f1.y); o.h[6] = f2b(f1.z); o.h[7] = f2b(f1.w);
  *(uint4*)(dst + (size_t)g * 8) = o.u;
}

// ---- prep: U/V [r][k][z] f32 -> fragment-major bf16 ----
__global__ __launch_bounds__(256) void fm_pack_B(const float* __restrict__ src,
                                                 u16* __restrict__ dst) {
  const int g  = blockIdx.x * 256 + threadIdx.x;      // chunk id
  const int c  = g & 1023;
  const int kt = (g >> 10) & 15;
  const int jt = (g >> 14) & 7;
  const int r  = g >> 17;
  const int l  = c & 63;
  const int kk = (c >> 6) & 1;
  const int nf = (c >> 7) & 1;
  const int wn = (c >> 8) & 3;
  const int j  = jt * 128 + wn * 32 + nf * 16 + (l & 15);
  const int kg = kt * 64 + kk * 32 + ((l >> 4) << 3);
  const float* s = src + (size_t)r * (D * Zq) + (size_t)kg * Zq + j;
  union { u16 h[8]; uint4 u; } o;
  #pragma unroll
  for (int e = 0; e < 8; ++e) o.h[e] = f2b(s[(size_t)e * Zq]);
  *(uint4*)(dst + (size_t)g * 8) = o.u;
}

#define GLDS(src, dst) __builtin_amdgcn_global_load_lds((gas_t)(src), (las_t)(dst), 16, 0, 0)
#define SFENCE() __builtin_amdgcn_sched_barrier(0)
#define BAR()    __builtin_amdgcn_s_barrier()
#define MFMA __builtin_amdgcn_mfma_f32_16x16x32_bf16

// one K-step = 4 phases; buf is compile-time (= s&1)
#define STEP(buf, s) do {                                                        \
  const u16* tA = sT[buf][0];                                                    \
  const u16* tB = sT[buf][1];                                                    \
  const bool pf1 = (s) + 1 < 256;                                                \
  const bool pf2 = (s) + 2 < 256;                                                \
  const int kn2 = ((s) + 2) & 15;                                                \
  const u16* upn = Ub + (size_t)(((s)+1) >> 4) * rstride + (((s)+1) & 15) * 8192;\
  const u16* vpn = Vb + (size_t)(((s)+1) >> 4) * rstride + (((s)+1) & 15) * 8192;\
  _Pragma("unroll")                                                              \
  for (int p = 0; p < 4; ++p) {                                                  \
    const int kk = p >> 1, mh = (p & 1) << 1;                                    \
    const int r0 = (((wm * 4 + mh) * 2 + kk) * 64 + lane) * 8;                   \
    bf16x8 a0 = *(const bf16x8*)(tA + r0);                                       \
    bf16x8 a1 = *(const bf16x8*)(tA + r0 + 1024);                                \
    bf16x8 b0 = *(const bf16x8*)(tB + r0);                                       \
    bf16x8 b1 = *(const bf16x8*)(tB + r0 + 1024);                                \
    if (p == 2 && pf1) {         /* kk0 B-regs free after ph1 -> reload (s+1) */ \
      bu[0][0] = *(const bf16x8*)(upn + bco[0][0]);                              \
      bu[1][0] = *(const bf16x8*)(upn + bco[1][0]);                              \
      bv[0][0] = *(const bf16x8*)(vpn + bco[0][0]);                              \
      bv[1][0] = *(const bf16x8*)(vpn + bco[1][0]);                              \
    }                                                                            \
    SFENCE();                                                                    \
    BAR();                                                                       \
    asm volatile("s_waitcnt lgkmcnt(0)" ::: "memory");                           \
    SFENCE();                                                                    \
    __builtin_amdgcn_s_setprio(1);                                               \
    au[mh][0]     = MFMA(a0, bu[0][kk], au[mh][0], 0, 0, 0);                     \
    av[mh][0]     = MFMA(b0, bv[0][kk], av[mh][0], 0, 0, 0);                     \
    au[mh][1]     = MFMA(a0, bu[1][kk], au[mh][1], 0, 0, 0);                     \
    av[mh][1]     = MFMA(b0, bv[1][kk], av[mh][1], 0, 0, 0);                     \
    au[mh + 1][0] = MFMA(a1, bu[0][kk], au[mh + 1][0], 0, 0, 0);                 \
    av[mh + 1][0] = MFMA(b1, bv[0][kk], av[mh + 1][0], 0, 0, 0);                 \
    au[mh + 1][1] = MFMA(a1, bu[1][kk], au[mh + 1][1], 0, 0, 0);                 \
    av[mh + 1][1] = MFMA(b1, bv[1][kk], av[mh + 1][1], 0, 0, 0);                 \
    __builtin_amdgcn_s_setprio(0);                                               \
    if (p == 3) {                                                                \
      if (pf1) {                 /* kk1 B-regs free after ph3 MFMAs */           \
        bu[0][1] = *(const bf16x8*)(upn + bco[0][1]);                            \
        bu[1][1] = *(const bf16x8*)(upn + bco[1][1]);                            \
        bv[0][1] = *(const bf16x8*)(vpn + bco[0][1]);                            \
        bv[1][1] = *(const bf16x8*)(vpn + bco[1][1]);                            \
      }                                                                          \
      if (pf2) {                 /* all waves passed ph3 bar -> buf readable done*/\
        GLDS(hdp + kn2 * 8192 + c0 * 8, &sT[buf][0][c0 * 8]);                    \
        GLDS(hdp + kn2 * 8192 + c1 * 8, &sT[buf][0][c1 * 8]);                    \
        GLDS(hpp + kn2 * 8192 + c0 * 8, &sT[buf][1][c0 * 8]);                    \
        GLDS(hpp + kn2 * 8192 + c1 * 8, &sT[buf][1][c1 * 8]);                    \
        SFENCE();                                                                \
        asm volatile("s_waitcnt vmcnt(12)" ::: "memory");                        \
      } else if ((s) == 254) {                                                   \
        SFENCE();                                                                \
        asm volatile("s_waitcnt vmcnt(8)" ::: "memory");                         \
      } else {                                                                   \
        SFENCE();                                                                \
        asm volatile("s_waitcnt vmcnt(0)" ::: "memory");                         \
      }                                                                          \
    }                                                                            \
    SFENCE();                                                                    \
    BAR();                                                                       \
    SFENCE();                                                                    \
  }                                                                              \
} while (0)

// ---- main: fused bilinear, bf16 MFMA 16x16x32 ----
// grid (32 bx, 8 jt) = 256 blocks = 1/CU. 512 thr = 8 waves (2m x 4n),
// wave tile 64x32 = 4mf x 2nf. A: LDS dbuf, staged distance-2. B: VGPR,
// distance-1 with in-step recycling. 4 fine phases per K-step.
__global__ __launch_bounds__(512, 2) void fused_bilinear(
    const u16* __restrict__ hdf, const u16* __restrict__ hpf,
    const u16* __restrict__ Uf, const u16* __restrict__ Vf,
    float* __restrict__ out)
{
  __shared__ __align__(16) u16 sT[2][2][128 * 64];   // 64 KB

  const int tid  = threadIdx.x;
  const int lane = tid & 63;
  const int wv   = tid >> 6;
  const int wm   = wv >> 2;               // 0..1
  const int wn   = wv & 3;                // 0..3

  const int bx = blockIdx.x;              // 0..31 (XCD = bx%8)
  const int jt = blockIdx.y;              // 0..7

  const u16* hdp = hdf + (size_t)bx * 16 * 8192;     // [kt][1024 chunks][8]
  const u16* hpp = hpf + (size_t)bx * 16 * 8192;
  const u16* Ub  = Uf + (size_t)jt * 16 * 8192;      // + r*rstride + kt*8192
  const u16* Vb  = Vf + (size_t)jt * 16 * 8192;
  const size_t rstride = (size_t)8 * 16 * 8192;

  const int c0 = wv * 128 + lane;
  const int c1 = c0 + 64;

  int bco[2][2];
  #pragma unroll
  for (int nf = 0; nf < 2; ++nf)
    #pragma unroll
    for (int kk = 0; kk < 2; ++kk)
      bco[nf][kk] = (((wn * 2 + nf) * 2 + kk) * 64 + lane) * 8;

  f32x4 acc[4][2], au[4][2], av[4][2];
  #pragma unroll
  for (int mf = 0; mf < 4; ++mf)
    #pragma unroll
    for (int nf = 0; nf < 2; ++nf) {
      acc[mf][nf] = (f32x4){0.f, 0.f, 0.f, 0.f};
      au[mf][nf]  = (f32x4){0.f, 0.f, 0.f, 0.f};
      av[mf][nf]  = (f32x4){0.f, 0.f, 0.f, 0.f};
    }

  bf16x8 bu[2][2], bv[2][2];   // [nf][kk], single set, recycled in-step

  // prologue: stage steps 0,1; load B(0); drain once; barrier.
  GLDS(hdp + 0 * 8192 + c0 * 8, &sT[0][0][c0 * 8]);
  GLDS(hdp + 0 * 8192 + c1 * 8, &sT[0][0][c1 * 8]);
  GLDS(hpp + 0 * 8192 + c0 * 8, &sT[0][1][c0 * 8]);
  GLDS(hpp + 0 * 8192 + c1 * 8, &sT[0][1][c1 * 8]);
  GLDS(hdp + 1 * 8192 + c0 * 8, &sT[1][0][c0 * 8]);
  GLDS(hdp + 1 * 8192 + c1 * 8, &sT[1][0][c1 * 8]);
  GLDS(hpp + 1 * 8192 + c0 * 8, &sT[1][1][c0 * 8]);
  GLDS(hpp + 1 * 8192 + c1 * 8, &sT[1][1][c1 * 8]);
  #pragma unroll
  for (int nf = 0; nf < 2; ++nf)
    #pragma unroll
    for (int kk = 0; kk < 2; ++kk) {
      bu[nf][kk] = *(const bf16x8*)(Ub + bco[nf][kk]);
      bv[nf][kk] = *(const bf16x8*)(Vb + bco[nf][kk]);
    }
  SFENCE();
  asm volatile("s_waitcnt vmcnt(0)" ::: "memory");
  SFENCE();
  BAR(); SFENCE();

  #pragma unroll 1
  for (int it = 0; it < 128; ++it) {
    const int s0 = it * 2;
    const int s1 = s0 + 1;

    STEP(0, s0);
    STEP(1, s1);

    // rank boundary every 16 steps (always lands on odd s1)
    if ((s1 & 15) == 15) {
      #pragma unroll
      for (int mf = 0; mf < 4; ++mf)
        #pragma unroll
        for (int nf = 0; nf < 2; ++nf) {
          #pragma unroll
          for (int i = 0; i < 4; ++i)
            acc[mf][nf][i] += au[mf][nf][i] * av[mf][nf][i];
          au[mf][nf] = (f32x4){0.f, 0.f, 0.f, 0.f};
          av[mf][nf] = (f32x4){0.f, 0.f, 0.f, 0.f};
        }
    }
  }

  // epilogue: store RAW sum (ReLU in LN). C/D: col = lane&15, row = 4*(lane>>4)+i.
  const int brow = bx * 128;
  const int jcol = jt * 128;
  #pragma unroll
  for (int mf = 0; mf < 4; ++mf)
    #pragma unroll
    for (int nf = 0; nf < 2; ++nf) {
      const int gr = brow + wm * 64 + mf * 16 + ((lane >> 4) << 2);
      const int gc = jcol + wn * 32 + nf * 16 + (lane & 15);
      #pragma unroll
      for (int i = 0; i < 4; ++i)
        out[(size_t)(gr + i) * Zq + gc] = acc[mf][nf][i];
    }
}

// ---- LayerNorm: z = relu(p); LN(z) -> out, in place. jnp.var ddof=0. ----
__global__ __launch_bounds__(256) void ln_rows(float* __restrict__ out,
    const float* __restrict__ gamma, const float* __restrict__ beta)
{
  const int row = blockIdx.x;
  const int t = threadIdx.x;
  float* o = out + (size_t)row * Zq;
  float4 v = ((const float4*)o)[t];
  v.x = fmaxf(v.x, 0.f); v.y = fmaxf(v.y, 0.f);
  v.z = fmaxf(v.z, 0.f); v.w = fmaxf(v.w, 0.f);
  float s = v.x + v.y + v.z + v.w;
  float q = v.x * v.x + v.y * v.y + v.z * v.z + v.w * v.w;
  #pragma unroll
  for (int off = 32; off > 0; off >>= 1) {
    s += __shfl_xor(s, off);
    q += __shfl_xor(q, off);
  }
  __shared__ float ss[4], sq[4];
  if ((t & 63) == 0) { ss[t >> 6] = s; sq[t >> 6] = q; }
  __syncthreads();
  s = ss[0] + ss[1] + ss[2] + ss[3];
  q = sq[0] + sq[1] + sq[2] + sq[3];
  const float mean = s * (1.f / Zq);
  float var = q * (1.f / Zq) - mean * mean;
  var = fmaxf(var, 0.f);
  const float rstd = rsqrtf(var + 1e-5f);
  const float4 g  = ((const float4*)gamma)[t];
  const float4 bb = ((const float4*)beta)[t];
  v.x = (v.x - mean) * rstd * g.x + bb.x;
  v.y = (v.y - mean) * rstd * g.y + bb.y;
  v.z = (v.z - mean) * rstd * g.z + bb.z;
  v.w = (v.w - mean) * rstd * g.w + bb.w;
  ((float4*)o)[t] = v;
}

// ---- fallback (tiny ws): plain f32, correct but slow ----
__global__ __launch_bounds__(256) void fallback_bilinear(
    const float* __restrict__ hd, const float* __restrict__ hp,
    const float* __restrict__ U, const float* __restrict__ V,
    float* __restrict__ out)
{
  const int j  = blockIdx.x * 256 + threadIdx.x;
  const int b0 = blockIdx.y * 8;
  float acc[8] = {0.f, 0.f, 0.f, 0.f, 0.f, 0.f, 0.f, 0.f};
  for (int r = 0; r < Rk; ++r) {
    float u[8] = {0.f}, v[8] = {0.f};
    const float* Up = U + (size_t)r * (D * Zq) + j;
    const float* Vp = V + (size_t)r * (D * Zq) + j;
    for (int k = 0; k < D; ++k) {
      const float uu = Up[(size_t)k * Zq];
      const float vv = Vp[(size_t)k * Zq];
      #pragma unroll
      for (int bi = 0; bi < 8; ++bi) {
        u[bi] = fmaf(hd[(size_t)(b0 + bi) * D + k], uu, u[bi]);
        v[bi] = fmaf(hp[(size_t)(b0 + bi) * D + k], vv, v[bi]);
      }
    }
    #pragma unroll
    for (int bi = 0; bi < 8; ++bi) acc[bi] += u[bi] * v[bi];
  }
  #pragma unroll
  for (int bi = 0; bi < 8; ++bi)
    out[(size_t)(b0 + bi) * Zq + j] = acc[bi];   // raw; ReLU in LN
}

extern "C" void kernel_launch(void* const* d_in, const int* in_sizes, int n_in,
                              void* d_out, int out_size, void* d_ws, size_t ws_size,
                              hipStream_t stream) {
  const float* hd    = (const float*)d_in[0];   // [4096][1024]
  const float* hp    = (const float*)d_in[1];   // [4096][1024]
  const float* U     = (const float*)d_in[2];   // [16][1024][1024]
  const float* V     = (const float*)d_in[3];   // [16][1024][1024]
  const float* gamma = (const float*)d_in[4];   // [1024]
  const float* beta  = (const float*)d_in[5];   // [1024]
  float* out = (float*)d_out;                   // [4096][1024] f32

  const size_t need = 80ull << 20;  // hd,hp fm (16MB) + U,V fm (64MB)
  if (ws_size >= need) {
    u16* hdf = (u16*)d_ws;                   // 4M elems
    u16* hpf = hdf + (size_t)Bq * D;
    u16* Ufm = hpf + (size_t)Bq * D;         // 16M elems each
    u16* Vfm = Ufm + (size_t)Rk * D * Zq;

    fm_pack_A<<<2048, 256, 0, stream>>>(hd, hdf);
    fm_pack_A<<<2048, 256, 0, stream>>>(hp, hpf);
    fm_pack_B<<<8192, 256, 0, stream>>>(U, Ufm);
    fm_pack_B<<<8192, 256, 0, stream>>>(V, Vfm);
    fused_bilinear<<<dim3(32, 8), 512, 0, stream>>>(hdf, hpf, Ufm, Vfm, out);
  } else {
    fallback_bilinear<<<dim3(Zq / 256, Bq / 8), 256, 0, stream>>>(hd, hp, U, V, out);
  }
  ln_rows<<<Bq, 256, 0, stream>>>(out, gamma, beta);
}